// Round 1
// baseline (110.658 us; speedup 1.0000x reference)
//
#include <hip/hip_runtime.h>
#include <math.h>

#define NBLK 784
#define O_ 32
#define N_ 144
#define D_ 16
#define PS 20    // padded LDS row stride for P (floats): 20n mod 32 distinct over n%8
#define RS 148   // padded LDS row stride for R (floats): 148o mod 32 distinct over o%8

__global__ __launch_bounds__(256) void convcaps_em(
    const float* __restrict__ poses,
    const float* __restrict__ acts,
    const float* __restrict__ kern,
    const float* __restrict__ beta_a,
    const float* __restrict__ beta_u,
    float* __restrict__ out)
{
    const int pix = blockIdx.x;          // b*196 + ho*14 + wo
    const int b  = pix / 196;
    const int hw = pix - b * 196;
    const int ho = hw / 14;
    const int wo = hw - ho * 14;

    __shared__ __align__(16) float P[N_ * PS];   // pose blocks [n][d]
    __shared__ float A[N_];                      // a_in
    __shared__ float Rm[O_ * RS];                // R / logits [o][n]

    const int t = threadIdx.x;

    // ---- load pose block: P[n][d] = poses[b, ho+ki, wo+kj, c, d], n=(ki*3+kj)*16+c
    for (int idx = t; idx < N_ * D_; idx += 256) {
        int n = idx >> 4, d = idx & 15;
        int ki = n / 48, kj = (n >> 4) - ki * 3, c = n & 15;
        P[n * PS + d] = poses[((b * 16 + ho + ki) * 16 + (wo + kj)) * 256 + c * 16 + d];
    }
    if (t < N_) {
        int n = t;
        int ki = n / 48, kj = (n >> 4) - ki * 3, c = n & 15;
        A[n] = acts[((b * 16 + ho + ki) * 16 + (wo + kj)) * 16 + c];
    }
    for (int idx = t; idx < O_ * N_; idx += 256) {
        int oo = idx / N_;
        int nn = idx - oo * N_;
        Rm[oo * RS + nn] = 0.03125f;             // 1/O
    }
    __syncthreads();

    const int o = t >> 3;                        // 32 capsules
    const int s = t & 7;                         // 8 lanes per capsule, n-slice
    const float bu = beta_u[o];
    const float ba = beta_a[o];
    const float* Kbase = kern + (size_t)o * (N_ * D_);

    float a_out = 0.f;
    float mu[16];

    for (int it = 0; it < 3; ++it) {
        // ===== pass 1: S1 = sum r*V, S2 = sum r*V^2, rs = sum r =====
        float S1[16], S2[16];
#pragma unroll
        for (int d = 0; d < 16; ++d) { S1[d] = 0.f; S2[d] = 0.f; }
        float rs = 0.f;

        for (int k = 0; k < 18; ++k) {
            const int n = s + (k << 3);
            const float r = Rm[o * RS + n] * A[n];
            rs += r;
            float pv[16], kv[16];
            const float4* Pp = (const float4*)(P + n * PS);
            ((float4*)pv)[0] = Pp[0];
            ((float4*)pv)[1] = Pp[1];
            ((float4*)pv)[2] = Pp[2];
            ((float4*)pv)[3] = Pp[3];
            const float4* Kp = (const float4*)(Kbase + n * D_);
            ((float4*)kv)[0] = Kp[0];
            ((float4*)kv)[1] = Kp[1];
            ((float4*)kv)[2] = Kp[2];
            ((float4*)kv)[3] = Kp[3];
#pragma unroll
            for (int i = 0; i < 4; ++i) {
#pragma unroll
                for (int l = 0; l < 4; ++l) {
                    // V[i*4+l] = sum_j P[n][i*4+j] * K[o,n][j*4+l]
                    float v = fmaf(pv[i*4+0], kv[0+l],
                              fmaf(pv[i*4+1], kv[4+l],
                              fmaf(pv[i*4+2], kv[8+l],
                                   pv[i*4+3] * kv[12+l])));
                    S1[i*4+l] = fmaf(r, v, S1[i*4+l]);
                    S2[i*4+l] = fmaf(r * v, v, S2[i*4+l]);
                }
            }
        }

        // allreduce over the 8 lanes sharing this o (butterfly)
#pragma unroll
        for (int m = 1; m < 8; m <<= 1) {
            rs += __shfl_xor(rs, m, 64);
#pragma unroll
            for (int d = 0; d < 16; ++d) {
                S1[d] += __shfl_xor(S1[d], m, 64);
                S2[d] += __shfl_xor(S2[d], m, 64);
            }
        }

        rs += 1e-9f;                              // r_sum = sum r + EPS
        const float inv_rs = 1.0f / rs;
        float sig[16];
#pragma unroll
        for (int d = 0; d < 16; ++d) {
            mu[d] = S1[d] * inv_rs;
            // sigma2 = E[V^2] - mu^2 + EPS  (== sum r (V-mu)^2 / rs + EPS)
            sig[d] = fmaf(-mu[d], mu[d], S2[d] * inv_rs) + 1e-9f;
        }
        // L = sum_d log(sigma2_d): each lane does its 2 d's, then reduce
        float lpart = logf(sig[2*s]) + logf(sig[2*s+1]);
#pragma unroll
        for (int m = 1; m < 8; m <<= 1) lpart += __shfl_xor(lpart, m, 64);
        const float L = lpart;
        // cost = rs * (D*beta_u + 0.5*L);  a_out = sigmoid(inv_temp*(ba - cost))
        const float cost = rs * fmaf(0.5f, L, 16.0f * bu);
        const float x = (float)(it + 1) * (ba - cost);
        a_out = 1.0f / (1.0f + expf(-x));

        if (it < 2) {
            float isig[16];
#pragma unroll
            for (int d = 0; d < 16; ++d) isig[d] = 1.0f / sig[d];
            // logits = log(a_out+eps) - 0.5*(D*log(2pi) + L) - 0.5*Q
            const float LC = logf(a_out + 1e-9f)
                           - 0.5f * (16.0f * 1.8378770664093453f + L);
            __syncthreads();   // all pass-1 reads of Rm done before overwrite

            // ===== pass 2: logits into Rm =====
            for (int k = 0; k < 18; ++k) {
                const int n = s + (k << 3);
                float pv[16], kv[16];
                const float4* Pp = (const float4*)(P + n * PS);
                ((float4*)pv)[0] = Pp[0];
                ((float4*)pv)[1] = Pp[1];
                ((float4*)pv)[2] = Pp[2];
                ((float4*)pv)[3] = Pp[3];
                const float4* Kp = (const float4*)(Kbase + n * D_);
                ((float4*)kv)[0] = Kp[0];
                ((float4*)kv)[1] = Kp[1];
                ((float4*)kv)[2] = Kp[2];
                ((float4*)kv)[3] = Kp[3];
                float Q = 0.f;
#pragma unroll
                for (int i = 0; i < 4; ++i) {
#pragma unroll
                    for (int l = 0; l < 4; ++l) {
                        float v = fmaf(pv[i*4+0], kv[0+l],
                                  fmaf(pv[i*4+1], kv[4+l],
                                  fmaf(pv[i*4+2], kv[8+l],
                                       pv[i*4+3] * kv[12+l])));
                        const float df = v - mu[i*4+l];
                        Q = fmaf(df * df, isig[i*4+l], Q);
                    }
                }
                Rm[o * RS + n] = fmaf(-0.5f, Q, LC);
            }
            __syncthreads();

            // ===== softmax over o, one thread per n =====
            if (t < N_) {
                float v[32];
                float mx = -1e30f;
#pragma unroll
                for (int oo = 0; oo < 32; ++oo) {
                    v[oo] = Rm[oo * RS + t];
                    mx = fmaxf(mx, v[oo]);
                }
                float sm = 0.f;
#pragma unroll
                for (int oo = 0; oo < 32; ++oo) {
                    v[oo] = expf(v[oo] - mx);
                    sm += v[oo];
                }
                const float inv = 1.0f / sm;
#pragma unroll
                for (int oo = 0; oo < 32; ++oo)
                    Rm[oo * RS + t] = v[oo] * inv;
            }
            __syncthreads();
        }
    }

    // ===== write outputs: poses [pix][o][16] then a_out [pix][o] =====
    float2 w2;
    w2.x = mu[2 * s];
    w2.y = mu[2 * s + 1];
    *(float2*)(out + (size_t)pix * 512 + o * 16 + 2 * s) = w2;
    if (s == 0) out[401408 + pix * 32 + o] = a_out;
}

extern "C" void kernel_launch(void* const* d_in, const int* in_sizes, int n_in,
                              void* d_out, int out_size, void* d_ws, size_t ws_size,
                              hipStream_t stream)
{
    const float* poses  = (const float*)d_in[0];
    const float* acts   = (const float*)d_in[1];
    const float* kern   = (const float*)d_in[2];
    const float* beta_a = (const float*)d_in[3];
    const float* beta_u = (const float*)d_in[4];
    float* out = (float*)d_out;
    convcaps_em<<<NBLK, 256, 0, stream>>>(poses, acts, kern, beta_a, beta_u, out);
}